// Round 1
// baseline (213.130 us; speedup 1.0000x reference)
//
#include <hip/hip_runtime.h>
#include <hip/hip_bf16.h>

#define B_ROWS 8192
#define C_IN   4096
#define G_GRP  8
#define CG     512
#define J_RANK 512

typedef __attribute__((ext_vector_type(8))) short bf16x8;
typedef __attribute__((ext_vector_type(4))) float f32x4;

struct ushort4v { unsigned short x, y, z, w; };

__device__ __forceinline__ unsigned short f2bf(float f) {
    unsigned int u = __float_as_uint(f);
    // round-to-nearest-even
    unsigned int r = (u + 0x7FFFu + ((u >> 16) & 1u)) >> 16;
    return (unsigned short)r;
}

// ---------------- kernel 1: convert weights fp32 -> bf16 ----------------
__global__ __launch_bounds__(256) void convert_w_kernel(
    const float* __restrict__ w, unsigned short* __restrict__ wb, int n4) {
    int i = blockIdx.x * 256 + threadIdx.x;
    if (i >= n4) return;
    float4 v = ((const float4*)w)[i];
    ushort4v o;
    o.x = f2bf(v.x); o.y = f2bf(v.y); o.z = f2bf(v.z); o.w = f2bf(v.w);
    ((ushort4v*)wb)[i] = o;
}

// -------- kernel 2: gather-permute x columns + convert to bf16 ----------
// block = (row b, 1024-column chunk cb). Reads scattered within one 16KB row
// (L1/L2 friendly), writes coalesced 8B/lane.
__global__ __launch_bounds__(256) void permute_x_kernel(
    const float* __restrict__ x, const int* __restrict__ arr,
    unsigned short* __restrict__ xp) {
    const int b  = blockIdx.x >> 2;
    const int cb = blockIdx.x & 3;
    const int p0 = cb * 1024 + threadIdx.x * 4;

    // arrangements declared int64 in the reference; harness contract says
    // int32. Detect: int64 little-endian => odd int32 words are all 0
    // (values < 4096). A genuine int32 permutation can't have 4 zeros.
    const bool is64 = (arr[1] == 0 && arr[3] == 0 && arr[5] == 0 && arr[7] == 0);

    const float* xrow = x + (size_t)b * C_IN;
    unsigned short tmp[4];
#pragma unroll
    for (int k = 0; k < 4; ++k) {
        int p = p0 + k;
        int s = is64 ? arr[2 * p] : arr[p];
        tmp[k] = f2bf(xrow[s]);
    }
    ushort4v o; o.x = tmp[0]; o.y = tmp[1]; o.z = tmp[2]; o.w = tmp[3];
    *(ushort4v*)(xp + (size_t)b * C_IN + p0) = o;
}

// ---------------- kernel 3: grouped GEMM (bf16 MFMA) ---------------------
// Per group g: out[:, g*512 + j] = Xp[:, g*512:(g+1)*512] @ Wb[g]^T + bias[g]
// 128x128 tile, BK=64, 4 waves each computing 64x64 (4x4 frags of 16x16x32).
__global__ __launch_bounds__(256) void gemm_kernel(
    const unsigned short* __restrict__ Xp,   // [B][4096] bf16 (permuted)
    const unsigned short* __restrict__ Wb,   // [G][J][CG] bf16
    const float* __restrict__ bias,          // [G][J]
    float* __restrict__ out) {               // [B][4096] fp32
    __shared__ unsigned short lds[2 * 128 * 64];
    unsigned short* ldsA = lds;
    unsigned short* ldsB = lds + 128 * 64;

    const int tid = threadIdx.x;
    const int gid = blockIdx.x;
    const int g   = gid >> 8;          // 256 blocks per group
    const int mt  = (gid & 255) >> 2;  // 64 m-tiles
    const int nt  = gid & 3;           // 4 n-tiles

    const int l  = tid & 63;
    const int wv = tid >> 6;           // wave 0..3
    const int wr = wv >> 1;            // wave row (0..1)
    const int wc = wv & 1;             // wave col (0..1)
    const int lr = l & 15;
    const int lk = (l >> 4) << 3;      // 0,8,16,24

    const unsigned short* Abase = Xp + (size_t)(mt * 128) * C_IN + g * CG;
    const unsigned short* Bbase = Wb + (size_t)g * J_RANK * CG + (size_t)(nt * 128) * CG;

    f32x4 acc[4][4];
#pragma unroll
    for (int m = 0; m < 4; ++m)
#pragma unroll
        for (int n = 0; n < 4; ++n) acc[m][n] = (f32x4){0.f, 0.f, 0.f, 0.f};

    for (int kb = 0; kb < CG / 64; ++kb) {
        // stage A tile (128x64 bf16 = 16KB): 1024 x 16B chunks, 4/thread
#pragma unroll
        for (int i = 0; i < 4; ++i) {
            int t = i * 256 + tid;
            int row = t >> 3;
            int cc  = t & 7;
            __builtin_amdgcn_global_load_lds(
                (const __attribute__((address_space(1))) unsigned int*)
                    (Abase + (size_t)row * C_IN + kb * 64 + cc * 8),
                (__attribute__((address_space(3))) unsigned int*)(ldsA + t * 8),
                16, 0, 0);
        }
        // stage B tile (128x64)
#pragma unroll
        for (int i = 0; i < 4; ++i) {
            int t = i * 256 + tid;
            int row = t >> 3;
            int cc  = t & 7;
            __builtin_amdgcn_global_load_lds(
                (const __attribute__((address_space(1))) unsigned int*)
                    (Bbase + (size_t)row * CG + kb * 64 + cc * 8),
                (__attribute__((address_space(3))) unsigned int*)(ldsB + t * 8),
                16, 0, 0);
        }
        __syncthreads();
#pragma unroll
        for (int kk = 0; kk < 2; ++kk) {
            bf16x8 af[4], bf[4];
#pragma unroll
            for (int m = 0; m < 4; ++m)
                af[m] = *(const bf16x8*)&ldsA[(wr * 64 + m * 16 + lr) * 64 + kk * 32 + lk];
#pragma unroll
            for (int n = 0; n < 4; ++n)
                bf[n] = *(const bf16x8*)&ldsB[(wc * 64 + n * 16 + lr) * 64 + kk * 32 + lk];
#pragma unroll
            for (int m = 0; m < 4; ++m)
#pragma unroll
                for (int n = 0; n < 4; ++n)
                    acc[m][n] = __builtin_amdgcn_mfma_f32_16x16x32_bf16(
                        af[m], bf[n], acc[m][n], 0, 0, 0);
        }
        __syncthreads();
    }

    // epilogue: D layout col = lane&15, row = (lane>>4)*4 + r  [m89-verified]
    const int r0 = mt * 128 + wr * 64 + ((l >> 4) << 2);
    const int c0 = nt * 128 + wc * 64 + lr;  // within this group's 512 cols
#pragma unroll
    for (int n = 0; n < 4; ++n) {
        int col = c0 + n * 16;
        float bv = bias[g * J_RANK + col];
#pragma unroll
        for (int m = 0; m < 4; ++m) {
            int row = r0 + m * 16;
            float* op = out + (size_t)row * C_IN + g * J_RANK + col;
#pragma unroll
            for (int r = 0; r < 4; ++r)
                op[(size_t)r * C_IN] = acc[m][n][r] + bv;
        }
    }
}

extern "C" void kernel_launch(void* const* d_in, const int* in_sizes, int n_in,
                              void* d_out, int out_size, void* d_ws, size_t ws_size,
                              hipStream_t stream) {
    const float* x    = (const float*)d_in[0];
    const int*   arr  = (const int*)d_in[1];
    const float* w    = (const float*)d_in[2];
    const float* bias = (const float*)d_in[3];
    float* out = (float*)d_out;

    // workspace layout: xp bf16 [8192][4096] (64MB) | wb bf16 [8][512][512] (4MB)
    unsigned short* xp = (unsigned short*)d_ws;
    unsigned short* wb = xp + (size_t)B_ROWS * C_IN;

    hipLaunchKernelGGL(convert_w_kernel, dim3((G_GRP * J_RANK * CG / 4 + 255) / 256),
                       dim3(256), 0, stream, w, wb, G_GRP * J_RANK * CG / 4);
    hipLaunchKernelGGL(permute_x_kernel, dim3(B_ROWS * 4), dim3(256), 0, stream,
                       x, arr, xp);
    hipLaunchKernelGGL(gemm_kernel, dim3(G_GRP * 256), dim3(256), 0, stream,
                       xp, wb, bias, out);
}

// Round 2
// 150.038 us; speedup vs baseline: 1.4205x; 1.4205x over previous
//
#include <hip/hip_runtime.h>
#include <hip/hip_bf16.h>

#define B_ROWS 8192
#define C_IN   4096
#define G_GRP  8
#define CG     512
#define J_RANK 512
#define BK     32
#define NKB    (CG / BK)   // 16 K-steps

typedef __attribute__((ext_vector_type(8))) short bf16x8;
typedef __attribute__((ext_vector_type(4))) float f32x4;
typedef __attribute__((ext_vector_type(8))) unsigned short u16x8;

struct ushort4v { unsigned short x, y, z, w; };

__device__ __forceinline__ unsigned short f2bf(float f) {
    unsigned int u = __float_as_uint(f);
    unsigned int r = (u + 0x7FFFu + ((u >> 16) & 1u)) >> 16;  // RNE
    return (unsigned short)r;
}

// ---------------- kernel 1: convert weights fp32 -> bf16 ----------------
__global__ __launch_bounds__(256) void convert_w_kernel(
    const float* __restrict__ w, unsigned short* __restrict__ wb, int n4) {
    int i = blockIdx.x * 256 + threadIdx.x;
    if (i >= n4) return;
    float4 v = ((const float4*)w)[i];
    ushort4v o;
    o.x = f2bf(v.x); o.y = f2bf(v.y); o.z = f2bf(v.z); o.w = f2bf(v.w);
    ((ushort4v*)wb)[i] = o;
}

// -------- kernel 2: gather-permute x via LDS row staging ----------------
// One block per row: coalesced float4 load of the 16KB row into LDS,
// gather from LDS (cheap), coalesced 16B bf16 stores.
__global__ __launch_bounds__(256) void permute_x_kernel(
    const float* __restrict__ x, const int* __restrict__ arr,
    unsigned short* __restrict__ xp) {
    __shared__ float row[C_IN];
    const int b = blockIdx.x;
    const float* xrow = x + (size_t)b * C_IN;

#pragma unroll
    for (int i = 0; i < 4; ++i) {
        int idx = i * 1024 + threadIdx.x * 4;
        *(float4*)&row[idx] = *(const float4*)&xrow[idx];
    }

    // arrangements declared int64 in the reference; harness may hand int32.
    // int64 little-endian => odd int32 words all 0 (values < 4096).
    const bool is64 = (arr[1] == 0 && arr[3] == 0 && arr[5] == 0 && arr[7] == 0);

    __syncthreads();

    unsigned short* orow = xp + (size_t)b * C_IN;
#pragma unroll
    for (int pass = 0; pass < 2; ++pass) {
        int p0 = pass * 2048 + threadIdx.x * 8;
        u16x8 o;
#pragma unroll
        for (int k = 0; k < 8; ++k) {
            int p = p0 + k;
            int s = is64 ? arr[2 * p] : arr[p];
            o[k] = f2bf(row[s]);
        }
        *(u16x8*)(orow + p0) = o;
    }
}

// ---------------- kernel 3: grouped GEMM (bf16 MFMA) ---------------------
// Per group g: out[:, g*512+j] = Xp[:, g*512:(g+1)*512] @ Wb[g]^T + bias[g]
// 128x256 tile, BK=32, double-buffered LDS with 2-phase prefetch
// (issue next-tile global_load_lds BEFORE computing current tile; one
// __syncthreads per K-step drains vmcnt after compute has hidden it).
__global__ __launch_bounds__(256) void gemm_kernel(
    const unsigned short* __restrict__ Xp,   // [B][4096] bf16 (permuted)
    const unsigned short* __restrict__ Wb,   // [G][J][CG] bf16
    const float* __restrict__ bias,          // [G][J]
    float* __restrict__ out) {               // [B][4096] fp32
    __shared__ unsigned short ldsA[2][128 * BK];   // 2 x 8KB
    __shared__ unsigned short ldsB[2][256 * BK];   // 2 x 16KB

    const int tid = threadIdx.x;
    // bijective XCD swizzle: 1024 blocks, 8 XCDs, 128 each
    const int lid = (blockIdx.x & 7) * 128 + (blockIdx.x >> 3);
    const int g   = lid >> 7;          // 8 groups x 128 blocks
    const int mt  = (lid & 127) >> 1;  // 64 m-tiles
    const int nt  = lid & 1;           // 2 n-tiles (256 cols each)

    const int l  = tid & 63;
    const int wv = tid >> 6;           // wave 0..3
    const int wr = wv >> 1;            // wave row 0..1 (64 rows each)
    const int wc = wv & 1;             // wave col 0..1 (128 cols each)
    const int lr = l & 15;
    const int lk = (l >> 4) << 3;      // k-slice 0,8,16,24

    const unsigned short* Abase = Xp + (size_t)(mt * 128) * C_IN + g * CG;
    const unsigned short* Bbase = Wb + (size_t)g * J_RANK * CG + (size_t)(nt * 256) * CG;

    f32x4 acc[4][8];
#pragma unroll
    for (int m = 0; m < 4; ++m)
#pragma unroll
        for (int n = 0; n < 8; ++n) acc[m][n] = (f32x4){0.f, 0.f, 0.f, 0.f};

#define STAGE(bufi, kb)                                                          \
    do {                                                                         \
        /* A: 128x32 bf16 = 512 x 16B chunks, 2/thread */                        \
        _Pragma("unroll")                                                        \
        for (int i = 0; i < 2; ++i) {                                            \
            int c = i * 256 + tid;                                               \
            int row = c >> 2, cc = c & 3;                                        \
            __builtin_amdgcn_global_load_lds(                                    \
                (const __attribute__((address_space(1))) unsigned int*)          \
                    (Abase + (size_t)row * C_IN + (kb) * BK + cc * 8),           \
                (__attribute__((address_space(3))) unsigned int*)                \
                    (&ldsA[bufi][0] + c * 8),                                    \
                16, 0, 0);                                                       \
        }                                                                        \
        /* B: 256x32 bf16 = 1024 x 16B chunks, 4/thread */                       \
        _Pragma("unroll")                                                        \
        for (int i = 0; i < 4; ++i) {                                            \
            int c = i * 256 + tid;                                               \
            int row = c >> 2, cc = c & 3;                                        \
            __builtin_amdgcn_global_load_lds(                                    \
                (const __attribute__((address_space(1))) unsigned int*)          \
                    (Bbase + (size_t)row * CG + (kb) * BK + cc * 8),             \
                (__attribute__((address_space(3))) unsigned int*)                \
                    (&ldsB[bufi][0] + c * 8),                                    \
                16, 0, 0);                                                       \
        }                                                                        \
    } while (0)

    STAGE(0, 0);
    __syncthreads();

    int buf = 0;
    for (int kb = 0; kb < NKB; ++kb) {
        if (kb + 1 < NKB) STAGE(buf ^ 1, kb + 1);

        bf16x8 af[4], bfr[8];
#pragma unroll
        for (int m = 0; m < 4; ++m)
            af[m] = *(const bf16x8*)&ldsA[buf][(wr * 64 + m * 16 + lr) * BK + lk];
#pragma unroll
        for (int n = 0; n < 8; ++n)
            bfr[n] = *(const bf16x8*)&ldsB[buf][(wc * 128 + n * 16 + lr) * BK + lk];
#pragma unroll
        for (int m = 0; m < 4; ++m)
#pragma unroll
            for (int n = 0; n < 8; ++n)
                acc[m][n] = __builtin_amdgcn_mfma_f32_16x16x32_bf16(
                    af[m], bfr[n], acc[m][n], 0, 0, 0);

        __syncthreads();   // drains vmcnt(0)+lgkmcnt(0): next buf staged, all reads done
        buf ^= 1;
    }
#undef STAGE

    // epilogue: D frag layout col = lane&15, row = (lane>>4)*4 + r
    const int r0 = mt * 128 + wr * 64 + ((l >> 4) << 2);
    const int cbase = nt * 256 + wc * 128 + lr;   // within group's 512 cols
#pragma unroll
    for (int n = 0; n < 8; ++n) {
        int col = cbase + n * 16;
        float bv = bias[g * J_RANK + col];
#pragma unroll
        for (int m = 0; m < 4; ++m) {
            int row = r0 + m * 16;
            float* op = out + (size_t)row * C_IN + g * J_RANK + col;
#pragma unroll
            for (int r = 0; r < 4; ++r)
                op[(size_t)r * C_IN] = acc[m][n][r] + bv;
        }
    }
}

extern "C" void kernel_launch(void* const* d_in, const int* in_sizes, int n_in,
                              void* d_out, int out_size, void* d_ws, size_t ws_size,
                              hipStream_t stream) {
    const float* x    = (const float*)d_in[0];
    const int*   arr  = (const int*)d_in[1];
    const float* w    = (const float*)d_in[2];
    const float* bias = (const float*)d_in[3];
    float* out = (float*)d_out;

    // workspace: xp bf16 [8192][4096] (64MB) | wb bf16 [8][512][512] (4MB)
    unsigned short* xp = (unsigned short*)d_ws;
    unsigned short* wb = xp + (size_t)B_ROWS * C_IN;

    hipLaunchKernelGGL(convert_w_kernel, dim3((G_GRP * J_RANK * CG / 4 + 255) / 256),
                       dim3(256), 0, stream, w, wb, G_GRP * J_RANK * CG / 4);
    hipLaunchKernelGGL(permute_x_kernel, dim3(B_ROWS), dim3(256), 0, stream,
                       x, arr, xp);
    hipLaunchKernelGGL(gemm_kernel, dim3(G_GRP * 128), dim3(256), 0, stream,
                       xp, wb, bias, out);
}

// Round 3
// 118.803 us; speedup vs baseline: 1.7940x; 1.2629x over previous
//
#include <hip/hip_runtime.h>
#include <hip/hip_bf16.h>

#define B_ROWS 8192
#define C_IN   4096
#define G_GRP  8
#define CG     512
#define J_RANK 512
#define BK     32
#define NKB    (CG / BK)   // 16 K-steps

#define RPB    4                      // rows per permute block
#define PERM_BLOCKS (B_ROWS / RPB)    // 2048

typedef __attribute__((ext_vector_type(8))) short bf16x8;
typedef __attribute__((ext_vector_type(4))) float f32x4;
typedef __attribute__((ext_vector_type(8))) unsigned short u16x8;

struct ushort4v { unsigned short x, y, z, w; };

__device__ __forceinline__ unsigned short f2bf(float f) {
    unsigned int u = __float_as_uint(f);
    unsigned int r = (u + 0x7FFFu + ((u >> 16) & 1u)) >> 16;  // RNE
    return (unsigned short)r;
}

// ---------------- kernel 1: convert weights fp32 -> bf16 ----------------
__global__ __launch_bounds__(256) void convert_w_kernel(
    const float* __restrict__ w, unsigned short* __restrict__ wb, int n4) {
    int i = blockIdx.x * 256 + threadIdx.x;
    if (i >= n4) return;
    float4 v = ((const float4*)w)[i];
    ushort4v o;
    o.x = f2bf(v.x); o.y = f2bf(v.y); o.z = f2bf(v.z); o.w = f2bf(v.w);
    ((ushort4v*)wb)[i] = o;
}

// -------- kernel 2: gather-permute x, pipelined multi-row ---------------
// 2048 blocks x 4 rows. arr indices hoisted to VGPRs once (identical for
// every row). x rows staged to LDS via global_load_lds (coalesced 16B),
// double-buffered 2 rows deep with COUNTED vmcnt waits (T4): load latency
// hides under the previous row's gather; vmcnt never drains to 0 mid-loop.
// Per-wave VMEM issue order: L0 L1 | S0 L2 | S1 L3 | S2 | S3
// (4 stage-loads + 2 gather-stores per row; vmcnt retires in order)
//   -> waits: r0: vmcnt(4)  r1,r2: vmcnt(6)  r3: vmcnt(2)
__global__ __launch_bounds__(256) void permute_x_kernel(
    const float* __restrict__ x, const int* __restrict__ arr,
    unsigned short* __restrict__ xp) {
    __shared__ float buf[2][C_IN];   // 2 x 16KB
    const int tid  = threadIdx.x;
    const int row0 = blockIdx.x * RPB;

    // arrangements declared int64 in the reference; harness may hand int32.
    // int64 little-endian => odd int32 words all 0 (values < 4096).
    const bool is64 = (arr[1] == 0 && arr[3] == 0 && arr[5] == 0 && arr[7] == 0);

    // hoist gather indices: thread t owns output positions
    // {pass*2048 + t*8 + k}, identical for all rows.
    int sidx[16];
#pragma unroll
    for (int pass = 0; pass < 2; ++pass)
#pragma unroll
        for (int k = 0; k < 8; ++k) {
            int p = pass * 2048 + tid * 8 + k;
            sidx[pass * 8 + k] = is64 ? arr[2 * p] : arr[p];
        }

#define PSTAGE(bufi, r)                                                      \
    do {                                                                     \
        const float* src_ = x + (size_t)(row0 + (r)) * C_IN;                 \
        _Pragma("unroll")                                                    \
        for (int i_ = 0; i_ < 4; ++i_) {                                     \
            int c_ = i_ * 256 + tid;                                         \
            __builtin_amdgcn_global_load_lds(                                \
                (const __attribute__((address_space(1))) unsigned int*)      \
                    (src_ + c_ * 4),                                         \
                (__attribute__((address_space(3))) unsigned int*)            \
                    (&buf[bufi][0] + c_ * 4),                                \
                16, 0, 0);                                                   \
        }                                                                    \
    } while (0)

    PSTAGE(0, 0);
    PSTAGE(1, 1);

#pragma unroll
    for (int r = 0; r < RPB; ++r) {
        if (r == 0)            asm volatile("s_waitcnt vmcnt(4)" ::: "memory");
        else if (r == RPB - 1) asm volatile("s_waitcnt vmcnt(2)" ::: "memory");
        else                   asm volatile("s_waitcnt vmcnt(6)" ::: "memory");
        __builtin_amdgcn_s_barrier();          // whole block's row r is in LDS
        __builtin_amdgcn_sched_barrier(0);

        const int bi = r & 1;
        unsigned short* orow = xp + (size_t)(row0 + r) * C_IN;
#pragma unroll
        for (int pass = 0; pass < 2; ++pass) {
            u16x8 o;
#pragma unroll
            for (int k = 0; k < 8; ++k)
                o[k] = f2bf(buf[bi][sidx[pass * 8 + k]]);
            *(u16x8*)(orow + pass * 2048 + tid * 8) = o;
        }

        __builtin_amdgcn_sched_barrier(0);
        __builtin_amdgcn_s_barrier();          // all waves done reading buf[bi]
        if (r + 2 < RPB) PSTAGE(bi, r + 2);    // safe to overwrite buf[bi]
    }
#undef PSTAGE
}

// ---------------- kernel 3: grouped GEMM (bf16 MFMA) ---------------------
// (unchanged from R1: 128x256 tile, BK=32, 2-phase double-buffered prefetch)
__global__ __launch_bounds__(256) void gemm_kernel(
    const unsigned short* __restrict__ Xp,   // [B][4096] bf16 (permuted)
    const unsigned short* __restrict__ Wb,   // [G][J][CG] bf16
    const float* __restrict__ bias,          // [G][J]
    float* __restrict__ out) {               // [B][4096] fp32
    __shared__ unsigned short ldsA[2][128 * BK];   // 2 x 8KB
    __shared__ unsigned short ldsB[2][256 * BK];   // 2 x 16KB

    const int tid = threadIdx.x;
    // bijective XCD swizzle: 1024 blocks, 8 XCDs, 128 each -> group g pinned
    // to XCD g; its 512KB B-panel stays L2-resident.
    const int lid = (blockIdx.x & 7) * 128 + (blockIdx.x >> 3);
    const int g   = lid >> 7;          // 8 groups x 128 blocks
    const int mt  = (lid & 127) >> 1;  // 64 m-tiles
    const int nt  = lid & 1;           // 2 n-tiles (256 cols each)

    const int l  = tid & 63;
    const int wv = tid >> 6;           // wave 0..3
    const int wr = wv >> 1;            // wave row 0..1 (64 rows each)
    const int wc = wv & 1;             // wave col 0..1 (128 cols each)
    const int lr = l & 15;
    const int lk = (l >> 4) << 3;      // k-slice 0,8,16,24

    const unsigned short* Abase = Xp + (size_t)(mt * 128) * C_IN + g * CG;
    const unsigned short* Bbase = Wb + (size_t)g * J_RANK * CG + (size_t)(nt * 256) * CG;

    f32x4 acc[4][8];
#pragma unroll
    for (int m = 0; m < 4; ++m)
#pragma unroll
        for (int n = 0; n < 8; ++n) acc[m][n] = (f32x4){0.f, 0.f, 0.f, 0.f};

#define STAGE(bufi, kb)                                                          \
    do {                                                                         \
        _Pragma("unroll")                                                        \
        for (int i = 0; i < 2; ++i) {                                            \
            int c = i * 256 + tid;                                               \
            int row = c >> 2, cc = c & 3;                                        \
            __builtin_amdgcn_global_load_lds(                                    \
                (const __attribute__((address_space(1))) unsigned int*)          \
                    (Abase + (size_t)row * C_IN + (kb) * BK + cc * 8),           \
                (__attribute__((address_space(3))) unsigned int*)                \
                    (&ldsA[bufi][0] + c * 8),                                    \
                16, 0, 0);                                                       \
        }                                                                        \
        _Pragma("unroll")                                                        \
        for (int i = 0; i < 4; ++i) {                                            \
            int c = i * 256 + tid;                                               \
            int row = c >> 2, cc = c & 3;                                        \
            __builtin_amdgcn_global_load_lds(                                    \
                (const __attribute__((address_space(1))) unsigned int*)          \
                    (Bbase + (size_t)row * CG + (kb) * BK + cc * 8),             \
                (__attribute__((address_space(3))) unsigned int*)                \
                    (&ldsB[bufi][0] + c * 8),                                    \
                16, 0, 0);                                                       \
        }                                                                        \
    } while (0)

    STAGE(0, 0);
    __syncthreads();

    int buf = 0;
    for (int kb = 0; kb < NKB; ++kb) {
        if (kb + 1 < NKB) STAGE(buf ^ 1, kb + 1);

        bf16x8 af[4], bfr[8];
#pragma unroll
        for (int m = 0; m < 4; ++m)
            af[m] = *(const bf16x8*)&ldsA[buf][(wr * 64 + m * 16 + lr) * BK + lk];
#pragma unroll
        for (int n = 0; n < 8; ++n)
            bfr[n] = *(const bf16x8*)&ldsB[buf][(wc * 128 + n * 16 + lr) * BK + lk];
#pragma unroll
        for (int m = 0; m < 4; ++m)
#pragma unroll
            for (int n = 0; n < 8; ++n)
                acc[m][n] = __builtin_amdgcn_mfma_f32_16x16x32_bf16(
                    af[m], bfr[n], acc[m][n], 0, 0, 0);

        __syncthreads();
        buf ^= 1;
    }
#undef STAGE

    // epilogue: D frag layout col = lane&15, row = (lane>>4)*4 + r
    const int r0 = mt * 128 + wr * 64 + ((l >> 4) << 2);
    const int cbase = nt * 256 + wc * 128 + lr;   // within group's 512 cols
#pragma unroll
    for (int n = 0; n < 8; ++n) {
        int col = cbase + n * 16;
        float bv = bias[g * J_RANK + col];
#pragma unroll
        for (int m = 0; m < 4; ++m) {
            int row = r0 + m * 16;
            float* op = out + (size_t)row * C_IN + g * J_RANK + col;
#pragma unroll
            for (int r = 0; r < 4; ++r)
                op[(size_t)r * C_IN] = acc[m][n][r] + bv;
        }
    }
}

extern "C" void kernel_launch(void* const* d_in, const int* in_sizes, int n_in,
                              void* d_out, int out_size, void* d_ws, size_t ws_size,
                              hipStream_t stream) {
    const float* x    = (const float*)d_in[0];
    const int*   arr  = (const int*)d_in[1];
    const float* w    = (const float*)d_in[2];
    const float* bias = (const float*)d_in[3];
    float* out = (float*)d_out;

    // workspace: xp bf16 [8192][4096] (64MB) | wb bf16 [8][512][512] (4MB)
    unsigned short* xp = (unsigned short*)d_ws;
    unsigned short* wb = xp + (size_t)B_ROWS * C_IN;

    hipLaunchKernelGGL(convert_w_kernel, dim3((G_GRP * J_RANK * CG / 4 + 255) / 256),
                       dim3(256), 0, stream, w, wb, G_GRP * J_RANK * CG / 4);
    hipLaunchKernelGGL(permute_x_kernel, dim3(PERM_BLOCKS), dim3(256), 0, stream,
                       x, arr, xp);
    hipLaunchKernelGGL(gemm_kernel, dim3(G_GRP * 128), dim3(256), 0, stream,
                       xp, wb, bias, out);
}